// Round 11
// baseline (165.855 us; speedup 1.0000x reference)
//
#include <hip/hip_runtime.h>
#include <hip/hip_bf16.h>

// SimpleTransformer: qkv = x @ W^T + b ; banded causal attention (window 129).
// B=4, T=4096, D=512, HISTORY=128. Inputs fp32, output fp32 (per reference).
// NEW (r11): cvt_kernel DELETED — qkv reads fp32 X/W directly and converts
// to bf16 during reg-staged LDS staging (T14 issue-early/write-late). Saves a
// full extra pass over X (~27MB HBM + ~9us wall). attn = r6-exact (best).
#define T_SEQ 4096
#define D_DIM 512
#define NBATCH 4
#define HIST 128

typedef short short8 __attribute__((ext_vector_type(8)));   // 8 x bf16 bits (4 VGPRs)
typedef float f32x4 __attribute__((ext_vector_type(4)));

static __device__ __forceinline__ f32x4 mfma_bf16(short8 a, short8 b, f32x4 c) {
  return __builtin_amdgcn_mfma_f32_16x16x32_bf16(a, b, c, 0, 0, 0);
}

static __device__ __forceinline__ ushort f2bf_bits(float f) {
  __hip_bfloat16 h = __float2bfloat16(f);
  return *reinterpret_cast<ushort*>(&h);
}

// ---------------------------------------------------------------------------
// Kernel 1: qkv[m][n] = sum_k X[m][k] * W[n][k] + bias[n]   (fp32 in, fused cvt)
//   M = 16384, N = 1536, K = 512. Tile 128x128, BK=64, 256 threads (2x2 waves).
//   Staging (reg-staged, fused convert): per K-step each thread owns 8 16B-LDS
//   chunks (4 A + 4 B). Loads for tile t+1 are ISSUED one iteration early
//   (float4 pairs -> 64 VGPR), converted + ds_write_b128 after the next
//   barrier — HBM/L2 latency hides under a full iteration of MFMA.
//   Same swizzled chunk map as r7 (LDS chunk c holds global (m, (c&7)^(m&7)))
//   so the conflict-free ds_read_b128 fragment reads are unchanged.
//   One raw s_barrier per iter; lgkmcnt(0) before it covers frag-reads AND
//   staging-writes (cross-wave visibility). vmcnt never explicitly drained —
//   compiler waits staged loads exactly at first use (reg dependence).
//   XCD-chunked bijective grid swizzle; r5-validated LDS-staged epilogue.
// ---------------------------------------------------------------------------
__global__ __launch_bounds__(256, 2)
void qkv_gemm_kernel(const float* __restrict__ X,
                     const float* __restrict__ W,
                     const float* __restrict__ bias,
                     ushort* __restrict__ Qo,
                     ushort* __restrict__ Ko,
                     ushort* __restrict__ Vt) {
  constexpr int BK = 64, KD = D_DIM;
  constexpr int NT = KD / BK;                       // 8 K-steps
  __shared__ __align__(16) ushort sA[2][128 * BK];  // 2 x 16 KB
  __shared__ __align__(16) ushort sB[2][128 * BK];  // 2 x 16 KB

  const int tid  = threadIdx.x;
  const int wave = tid >> 6, lane = tid & 63;
  const int col  = lane & 15, quad = lane >> 4;
  // XCD-chunked swizzle: 1536 blocks, 8 XCDs, 192 logical/XCD, n fastest.
  const int lb = (blockIdx.x & 7) * 192 + (blockIdx.x >> 3);
  const int m0 = (lb / 12) * 128;
  const int n0 = (lb % 12) * 128;
  const int wm = (wave >> 1) * 64, wn = (wave & 1) * 64;

  // Per-thread staging chunks (r7 map): LDS chunk c holds global (m, kq) with
  // m = c>>3, kq = (c&7)^(m&7).
  const float* gA[4];
  const float* gB[4];
  int lc[4];
#pragma unroll
  for (int j = 0; j < 4; ++j) {
    const int c  = wave * 256 + j * 64 + lane;
    const int m  = c >> 3;
    const int kq = (c & 7) ^ (m & 7);
    lc[j] = c;
    gA[j] = X + (size_t)(m0 + m) * KD + kq * 8;
    gB[j] = W + (size_t)(n0 + m) * KD + kq * 8;
  }

  float4 ra[4][2], rb[4][2];   // staged fp32 for the NEXT tile (64 VGPR)
  auto issue = [&](int t) {
#pragma unroll
    for (int j = 0; j < 4; ++j) {
      ra[j][0] = *(const float4*)(gA[j] + t * BK);
      ra[j][1] = *(const float4*)(gA[j] + t * BK + 4);
      rb[j][0] = *(const float4*)(gB[j] + t * BK);
      rb[j][1] = *(const float4*)(gB[j] + t * BK + 4);
    }
  };
  auto cvt_write = [&](int buf) {
#pragma unroll
    for (int j = 0; j < 4; ++j) {
      short8 va, vb;
      va[0] = f2bf_bits(ra[j][0].x); va[1] = f2bf_bits(ra[j][0].y);
      va[2] = f2bf_bits(ra[j][0].z); va[3] = f2bf_bits(ra[j][0].w);
      va[4] = f2bf_bits(ra[j][1].x); va[5] = f2bf_bits(ra[j][1].y);
      va[6] = f2bf_bits(ra[j][1].z); va[7] = f2bf_bits(ra[j][1].w);
      vb[0] = f2bf_bits(rb[j][0].x); vb[1] = f2bf_bits(rb[j][0].y);
      vb[2] = f2bf_bits(rb[j][0].z); vb[3] = f2bf_bits(rb[j][0].w);
      vb[4] = f2bf_bits(rb[j][1].x); vb[5] = f2bf_bits(rb[j][1].y);
      vb[6] = f2bf_bits(rb[j][1].z); vb[7] = f2bf_bits(rb[j][1].w);
      *(short8*)(&sA[buf][lc[j] * 8]) = va;
      *(short8*)(&sB[buf][lc[j] * 8]) = vb;
    }
  };

  f32x4 acc[4][4];
#pragma unroll
  for (int i = 0; i < 4; ++i)
#pragma unroll
    for (int j = 0; j < 4; ++j) acc[i][j] = (f32x4)0.0f;

  // prologue: tile 0 -> regs -> buf0; issue tile 1 loads.
  issue(0);
  cvt_write(0);                        // compiler waits the loads at first use
  issue(1);
  asm volatile("s_waitcnt lgkmcnt(0)" ::: "memory");   // buf0 writes landed
  __builtin_amdgcn_s_barrier();

#pragma unroll
  for (int t = 0; t < NT; ++t) {
    // frag reads of tile t (buf[t&1]) — other buffer is written this iter
    const ushort* cA = sA[t & 1];
    const ushort* cB = sB[t & 1];
    short8 af[2][4], bf[2][4];
#pragma unroll
    for (int ks = 0; ks < 2; ++ks) {
      const int kq = ks * 4 + quad;
#pragma unroll
      for (int mt = 0; mt < 4; ++mt) {
        const int m = wm + mt * 16 + col;
        af[ks][mt] = *(const short8*)(&cA[(m * 8 + (kq ^ (m & 7))) * 8]);
        const int n = wn + mt * 16 + col;
        bf[ks][mt] = *(const short8*)(&cB[(n * 8 + (kq ^ (n & 7))) * 8]);
      }
    }
    if (t + 1 < NT) cvt_write((t + 1) & 1);  // staged loads -> bf16 -> LDS
    if (t + 2 < NT) issue(t + 2);            // refill staging regs (not waited)

    asm volatile("s_waitcnt lgkmcnt(0)" ::: "memory");  // frags in regs + writes landed
    __builtin_amdgcn_s_setprio(1);
#pragma unroll
    for (int ks = 0; ks < 2; ++ks)
#pragma unroll
      for (int mt = 0; mt < 4; ++mt)
#pragma unroll
        for (int nt = 0; nt < 4; ++nt)
          acc[mt][nt] = mfma_bf16(af[ks][mt], bf[ks][nt], acc[mt][nt]);
    __builtin_amdgcn_s_setprio(0);
    if (t < NT - 1) __builtin_amdgcn_s_barrier();  // writes visible; reads done
  }
  __builtin_amdgcn_s_barrier();        // all waves' final reads done (epilogue reuses LDS)

  // ---- epilogue: per-wave 64x64 bf16 tile via LDS, 16B/lane stores ----
  ushort* eL = &sA[0][0] + wave * 4096;
  const int region = n0 >> 9;   // 0=Q, 1=K, 2=V (tiles never straddle)

  if (region < 2) {
#pragma unroll
    for (int nt = 0; nt < 4; ++nt) {
      const float bv = bias[n0 + wn + nt * 16 + col];
      const int cl = nt * 16 + col;
#pragma unroll
      for (int mt = 0; mt < 4; ++mt) {
        const int rb2 = mt * 16 + quad * 4;
#pragma unroll
        for (int r = 0; r < 4; ++r) {
          const int R = rb2 + r;
          eL[R * 64 + (((cl >> 3) ^ (R & 7)) * 8) + (cl & 7)] =
              f2bf_bits(acc[mt][nt][r] + bv);
        }
      }
    }
    ushort* __restrict__ Out = (region == 0) ? Qo : Ko;
    const int rgrp = lane >> 3, cch = lane & 7;
    const int phys = cch ^ rgrp;
    const int dbase = (n0 & (D_DIM - 1)) + wn + cch * 8;
#pragma unroll
    for (int j = 0; j < 8; ++j) {
      const int R = j * 8 + rgrp;
      const short8 v = *(const short8*)(&eL[R * 64 + phys * 8]);
      *(short8*)(&Out[(size_t)(m0 + wm + R) * D_DIM + dbase]) = v;
    }
  } else {
#pragma unroll
    for (int nt = 0; nt < 4; ++nt) {
      const float bv = bias[n0 + wn + nt * 16 + col];
      const int dl = nt * 16 + col;
#pragma unroll
      for (int mt = 0; mt < 4; ++mt) {
        const int rb2 = mt * 16 + quad * 4;
#pragma unroll
        for (int r = 0; r < 4; ++r) {
          const int tl = rb2 + r;
          eL[dl * 64 + (((tl >> 3) ^ (dl & 7)) * 8) + (tl & 7)] =
              f2bf_bits(acc[mt][nt][r] + bv);
        }
      }
    }
    const int rgrp = lane >> 3, cch = lane & 7;
    const int phys = cch ^ rgrp;
    const int mr0 = m0 + wm;
    const int bb  = mr0 >> 12;
    const int tt0 = (mr0 & (T_SEQ - 1)) + cch * 8;
#pragma unroll
    for (int j = 0; j < 8; ++j) {
      const int dl = j * 8 + rgrp;
      const short8 v = *(const short8*)(&eL[dl * 64 + phys * 8]);
      const int d = (n0 & (D_DIM - 1)) + wn + dl;
      *(short8*)(&Vt[((size_t)bb * D_DIM + d) * T_SEQ + tt0]) = v;
    }
  }
}

// ---------------------------------------------------------------------------
// Kernel 2: banded attention — r6-exact (best measured: 51.6 -> <41us).
//   256 blocks x 512 thr, 64-row tiles, 192-key span; XCD swizzle; PD=4
//   register prefetch in QK^T; V loads issued before softmax barriers
//   (vmcnt never drained); packed-uint P writes.
// ---------------------------------------------------------------------------
__global__ __launch_bounds__(512, 2)
void attn_kernel(const ushort* __restrict__ Qb,
                 const ushort* __restrict__ Kb,
                 const ushort* __restrict__ Vtb,
                 float* __restrict__ out) {
  constexpr int SLD = 193;   // fp32 stride (odd) -> conflict-free softmax sweeps
  constexpr int PLD = 200;   // bf16 stride, 400B rows (16B aligned)
  __shared__ float  S[64 * SLD];   // 49408 B
  __shared__ ushort P[64 * PLD];   // 25600 B

  const int tid  = threadIdx.x;
  const int wave = tid >> 6, lane = tid & 63;
  const int col  = lane & 15, quad = lane >> 4;
  // XCD-aware bijective swizzle (grid 256, 8 XCDs -> 32 consecutive tiles/XCD)
  const int l  = (blockIdx.x & 7) * 32 + (blockIdx.x >> 3);
  const int b  = l >> 6;
  const int t0 = (l & 63) * 64;
  const int s0 = t0 - HIST;

  const ushort* Qp = Qb  + (size_t)b * T_SEQ * D_DIM;
  const ushort* Kp = Kb  + (size_t)b * T_SEQ * D_DIM;
  const ushort* Vp = Vtb + (size_t)b * D_DIM * T_SEQ;

  // ---- phase 1: S[64][192] = Q K^T ----
  const int wr = wave >> 2;    // 0..1 : 32-row group
  const int wc = wave & 3;     // 0..3 : 48-col group
  const ushort* qp0 = Qp + (size_t)(t0 + wr * 32 + col) * D_DIM;
  const ushort* qp1 = qp0 + 16 * D_DIM;
  const ushort* kp[3];
#pragma unroll
  for (int st = 0; st < 3; ++st) {
    int sg = s0 + wc * 48 + st * 16 + col;
    sg = sg < 0 ? 0 : sg;                // clamped keys masked in softmax
    kp[st] = Kp + (size_t)sg * D_DIM;
  }

  f32x4 sacc[2][3];
#pragma unroll
  for (int i = 0; i < 2; ++i)
#pragma unroll
    for (int j = 0; j < 3; ++j) sacc[i][j] = (f32x4)0.0f;

  constexpr int PD = 4;                  // prefetch depth (5 loads/iter -> 15 in flight)
  short8 qf[PD][2], kf[PD][3];
#pragma unroll
  for (int d = 0; d < PD; ++d) {
    const int kk = d * 32 + quad * 8;
    qf[d][0] = *(const short8*)(qp0 + kk);
    qf[d][1] = *(const short8*)(qp1 + kk);
#pragma unroll
    for (int st = 0; st < 3; ++st)
      kf[d][st] = *(const short8*)(kp[st] + kk);
  }
#pragma unroll
  for (int ks = 0; ks < 16; ++ks) {      // K = 512 = 16 * 32
    const int slot = ks & 3;             // compile-time (fully unrolled)
    __builtin_amdgcn_s_setprio(1);
#pragma unroll
    for (int st = 0; st < 3; ++st) {
      sacc[0][st] = mfma_bf16(qf[slot][0], kf[slot][st], sacc[0][st]);
      sacc[1][st] = mfma_bf16(qf[slot][1], kf[slot][st], sacc[1][st]);
    }
    __builtin_amdgcn_s_setprio(0);
    if (ks + PD < 16) {
      const int kk = (ks + PD) * 32 + quad * 8;
      qf[slot][0] = *(const short8*)(qp0 + kk);
      qf[slot][1] = *(const short8*)(qp1 + kk);
#pragma unroll
      for (int st = 0; st < 3; ++st)
        kf[slot][st] = *(const short8*)(kp[st] + kk);
    }
  }
  const float scale = 0.04419417382415922f;   // 1/sqrt(512)
#pragma unroll
  for (int mt = 0; mt < 2; ++mt)
#pragma unroll
    for (int st = 0; st < 3; ++st) {
      const int row = wr * 32 + mt * 16 + quad * 4;
      const int c   = wc * 48 + st * 16 + col;
#pragma unroll
      for (int r = 0; r < 4; ++r)
        S[(row + r) * SLD + c] = sacc[mt][st][r] * scale;
    }

  // Issue nt=0 V loads NOW (independent of softmax); they fly across the
  // barriers below because we never drain vmcnt.
  const ushort* vbase = Vp + (size_t)(wave * 64 + col) * T_SEQ;
  short8 vf[2][6];
#pragma unroll
  for (int k = 0; k < 6; ++k) {
    int sg = s0 + k * 32 + quad * 8;
    sg = sg < 0 ? 0 : sg;                // P is 0 there
    vf[0][k] = *(const short8*)(vbase + sg);
  }

  asm volatile("s_waitcnt lgkmcnt(0)" ::: "memory");  // S stores visible
  __builtin_amdgcn_s_barrier();

  // ---- banded softmax: 8 threads per row, 24 cols each ----
  {
    const int row  = tid >> 3, part = tid & 7;
    const int lo = max(row, HIST - t0);   // j_local >= row and key >= 0
    const int hi = row + HIST;            // causal end (<= 191)
    float* Srow = S + row * SLD;
    const int j0 = part * 24;
    float mx = -3.0e38f;
    for (int j = j0; j < j0 + 24; ++j)
      if (j >= lo && j <= hi) mx = fmaxf(mx, Srow[j]);
    mx = fmaxf(mx, __shfl_xor(mx, 1));
    mx = fmaxf(mx, __shfl_xor(mx, 2));
    mx = fmaxf(mx, __shfl_xor(mx, 4));
    float sum = 0.f;
    for (int j = j0; j < j0 + 24; ++j) {
      if (j >= lo && j <= hi) {
        const float e = __expf(Srow[j] - mx);
        Srow[j] = e;
        sum += e;
      }
    }
    sum += __shfl_xor(sum, 1);
    sum += __shfl_xor(sum, 2);
    sum += __shfl_xor(sum, 4);
    const float inv = 1.0f / sum;
    uint* Prow32 = (uint*)(P + row * PLD);   // 400B rows -> 4B aligned
#pragma unroll
    for (int i = 0; i < 12; ++i) {
      const int j = j0 + 2 * i;
      const float v0 = (j     >= lo && j     <= hi) ? Srow[j]     * inv : 0.0f;
      const float v1 = (j + 1 >= lo && j + 1 <= hi) ? Srow[j + 1] * inv : 0.0f;
      Prow32[part * 12 + i] = (uint)f2bf_bits(v0) | ((uint)f2bf_bits(v1) << 16);
    }
  }
  asm volatile("s_waitcnt lgkmcnt(0)" ::: "memory");  // P writes visible
  __builtin_amdgcn_s_barrier();

  // ---- phase 2: O[64][512] = P[64][192] @ V[192][512], 64 d-cols/wave ----
#pragma unroll
  for (int nt = 0; nt < 4; ++nt) {
    const int cb = nt & 1;
    if (nt < 3) {                        // prefetch next nt's V frags
#pragma unroll
      for (int k = 0; k < 6; ++k) {
        int sg = s0 + k * 32 + quad * 8;
        sg = sg < 0 ? 0 : sg;
        vf[cb ^ 1][k] = *(const short8*)(vbase + (size_t)(nt + 1) * 16 * T_SEQ + sg);
      }
    }
    f32x4 oacc[4];
#pragma unroll
    for (int i = 0; i < 4; ++i) oacc[i] = (f32x4)0.0f;
#pragma unroll
    for (int k = 0; k < 6; ++k) {        // 192 = 6 * 32
      __builtin_amdgcn_s_setprio(1);
#pragma unroll
      for (int mt = 0; mt < 4; ++mt) {
        const short8 af = *(const short8*)(&P[(mt * 16 + col) * PLD + k * 32 + quad * 8]);
        oacc[mt] = mfma_bf16(af, vf[cb][k], oacc[mt]);
      }
      __builtin_amdgcn_s_setprio(0);
    }
    const int d = wave * 64 + nt * 16 + col;
#pragma unroll
    for (int mt = 0; mt < 4; ++mt) {
      const int mg = t0 + mt * 16 + quad * 4;
#pragma unroll
      for (int r = 0; r < 4; ++r)
        out[((size_t)b * T_SEQ + mg + r) * D_DIM + d] = oacc[mt][r];
    }
  }
}

// ---------------------------------------------------------------------------
extern "C" void kernel_launch(void* const* d_in, const int* in_sizes, int n_in,
                              void* d_out, int out_size, void* d_ws, size_t ws_size,
                              hipStream_t stream) {
  const float* X    = (const float*)d_in[0];   // (B*T, 512) fp32
  const float* W    = (const float*)d_in[1];   // (1536, 512) fp32
  const float* bias = (const float*)d_in[2];   // (1536,) fp32

  // ws layout (bf16/ushort): Q | K | Vt   (~50 MB; cvt buffers eliminated)
  const size_t NX = (size_t)NBATCH * T_SEQ * D_DIM;   // 8388608
  ushort* Qw = (ushort*)d_ws;
  ushort* Kw = Qw + NX;
  ushort* Vw = Kw + NX;

  dim3 g1(1536), b1(256);   // linear grid; XCD-chunked swizzle in-kernel
  qkv_gemm_kernel<<<g1, b1, 0, stream>>>(X, W, bias, Qw, Kw, Vw);

  dim3 g2(NBATCH * (T_SEQ / 64)), b2(512);
  attn_kernel<<<g2, b2, 0, stream>>>(Qw, Kw, Vw, (float*)d_out);
}

// Round 12
// 149.185 us; speedup vs baseline: 1.1117x; 1.1117x over previous
//
#include <hip/hip_runtime.h>
#include <hip/hip_bf16.h>

// SimpleTransformer: qkv = x @ W^T + b ; banded causal attention (window 129).
// B=4, T=4096, D=512, HISTORY=128. Inputs fp32, output fp32 (per reference).
// ROUND-7 RESTORE (best measured total 147.6us). r11's fused-cvt regressed
// qkv 42->81us: fp32 re-reads doubled FETCH (28.5->58MB), VGPR 72->124,
// reg-staging put cvt+ds_write on the critical path (+131K bank conflicts).
// The separate bf16 cvt pass pays for itself because X is re-read 12x at
// half the bytes.
#define T_SEQ 4096
#define D_DIM 512
#define NBATCH 4
#define HIST 128

typedef short short8 __attribute__((ext_vector_type(8)));   // 8 x bf16 bits (4 VGPRs)
typedef float f32x4 __attribute__((ext_vector_type(4)));

static __device__ __forceinline__ f32x4 mfma_bf16(short8 a, short8 b, f32x4 c) {
  return __builtin_amdgcn_mfma_f32_16x16x32_bf16(a, b, c, 0, 0, 0);
}

static __device__ __forceinline__ ushort f2bf_bits(float f) {
  __hip_bfloat16 h = __float2bfloat16(f);
  return *reinterpret_cast<ushort*>(&h);
}

// Async 16B-per-lane global->LDS DMA. LDS dest is wave-uniform base + lane*16.
static __device__ __forceinline__ void gload_lds16(const ushort* g, ushort* l) {
  __builtin_amdgcn_global_load_lds(
      (__attribute__((address_space(1))) void*)g,
      (__attribute__((address_space(3))) void*)l, 16, 0, 0);
}

// ---------------------------------------------------------------------------
// Kernel 0: fp32 -> bf16 conversion, 16 elems (64B read / 32B write) per thread.
// ---------------------------------------------------------------------------
__global__ __launch_bounds__(256)
void cvt_kernel(const float* __restrict__ X, const float* __restrict__ W,
                ushort* __restrict__ Xb, ushort* __restrict__ Wb) {
  constexpr size_t NX = (size_t)NBATCH * T_SEQ * D_DIM;   // 8388608
  const size_t off = ((size_t)blockIdx.x * 256 + threadIdx.x) * 16;
  const float* s;
  ushort* d;
  if (off < NX) { s = X + off; d = Xb + off; }     // regions 16-aligned: no straddle
  else          { s = W + (off - NX); d = Wb + (off - NX); }
#pragma unroll
  for (int h = 0; h < 2; ++h) {
    const float4 a = *(const float4*)(s + h * 8);
    const float4 b = *(const float4*)(s + h * 8 + 4);
    short8 v;
    v[0] = f2bf_bits(a.x); v[1] = f2bf_bits(a.y);
    v[2] = f2bf_bits(a.z); v[3] = f2bf_bits(a.w);
    v[4] = f2bf_bits(b.x); v[5] = f2bf_bits(b.y);
    v[6] = f2bf_bits(b.z); v[7] = f2bf_bits(b.w);
    *(short8*)(d + h * 8) = v;
  }
}

// ---------------------------------------------------------------------------
// Kernel 1: qkv[m][n] = sum_k X[m][k] * W[n][k] + bias[n]   (bf16 in, fp32 acc)
//   M = 16384, N = 1536, K = 512. Tile 128x128, BK=64, 256 threads (2x2 waves).
//   Linear 1536-block grid with XCD-chunked bijective swizzle: XCD c owns
//   logical blocks [c*192,(c+1)*192), ordered n-fastest (X-tile L2 reuse).
//   K-loop: 2-deep pipeline, raw s_barrier + counted s_waitcnt vmcnt(8).
//   Staging via global_load_lds dwordx4; LDS dest LINEAR, XOR swizzle
//   (kq ^ (m&7)) on the per-lane GLOBAL source (involution) -> conflict-free
//   ds_read_b128 fragment reads (measured 0 conflicts).
//   Epilogue: per-wave 64x64 bf16 tile via LDS, 16B/lane stores (WRITE fix:
//   95 -> ~50MB).
// ---------------------------------------------------------------------------
__global__ __launch_bounds__(256, 2)
void qkv_gemm_kernel(const ushort* __restrict__ X,
                     const ushort* __restrict__ W,
                     const float* __restrict__ bias,
                     ushort* __restrict__ Qo,
                     ushort* __restrict__ Ko,
                     ushort* __restrict__ Vt) {
  constexpr int BK = 64, KD = D_DIM;
  constexpr int NT = KD / BK;                       // 8 K-steps
  __shared__ __align__(16) ushort sA[2][128 * BK];  // 2 x 16 KB
  __shared__ __align__(16) ushort sB[2][128 * BK];  // 2 x 16 KB

  const int tid  = threadIdx.x;
  const int wave = tid >> 6, lane = tid & 63;
  const int col  = lane & 15, quad = lane >> 4;
  // XCD-chunked swizzle: 1536 blocks, 8 XCDs, 192 logical/XCD, n fastest.
  const int lb = (blockIdx.x & 7) * 192 + (blockIdx.x >> 3);
  const int m0 = (lb / 12) * 128;
  const int n0 = (lb % 12) * 128;
  const int wm = (wave >> 1) * 64, wn = (wave & 1) * 64;

  const ushort* gA[4];
  const ushort* gB[4];
#pragma unroll
  for (int j = 0; j < 4; ++j) {
    const int c  = wave * 256 + j * 64 + lane;
    const int m  = c >> 3;
    const int kq = (c & 7) ^ (m & 7);
    gA[j] = X + (size_t)(m0 + m) * KD + kq * 8;
    gB[j] = W + (size_t)(n0 + m) * KD + kq * 8;
  }

  auto stage = [&](int buf, int t) {
#pragma unroll
    for (int j = 0; j < 4; ++j) {
      gload_lds16(gA[j] + t * BK, &sA[buf][(wave * 256 + j * 64) * 8]);
      gload_lds16(gB[j] + t * BK, &sB[buf][(wave * 256 + j * 64) * 8]);
    }
  };

  f32x4 acc[4][4];
#pragma unroll
  for (int i = 0; i < 4; ++i)
#pragma unroll
    for (int j = 0; j < 4; ++j) acc[i][j] = (f32x4)0.0f;

  stage(0, 0);
  stage(1, 1);

#pragma unroll
  for (int t = 0; t < NT; ++t) {
    if (t < NT - 1) asm volatile("s_waitcnt vmcnt(8)" ::: "memory");
    else            asm volatile("s_waitcnt vmcnt(0)" ::: "memory");
    __builtin_amdgcn_s_barrier();        // tile t visible to all waves

    const ushort* cA = sA[t & 1];
    const ushort* cB = sB[t & 1];
    short8 af[2][4], bf[2][4];
#pragma unroll
    for (int ks = 0; ks < 2; ++ks) {
      const int kq = ks * 4 + quad;
#pragma unroll
      for (int mt = 0; mt < 4; ++mt) {
        const int m = wm + mt * 16 + col;
        af[ks][mt] = *(const short8*)(&cA[(m * 8 + (kq ^ (m & 7))) * 8]);
        const int n = wn + mt * 16 + col;
        bf[ks][mt] = *(const short8*)(&cB[(n * 8 + (kq ^ (n & 7))) * 8]);
      }
    }
    asm volatile("s_waitcnt lgkmcnt(0)" ::: "memory");  // reads done (in regs)
    __builtin_amdgcn_s_barrier();        // all waves done reading buf[t&1]

    if (t + 2 < NT) stage(t & 1, t + 2); // overwrite safe; not waited

    __builtin_amdgcn_s_setprio(1);
#pragma unroll
    for (int ks = 0; ks < 2; ++ks)
#pragma unroll
      for (int mt = 0; mt < 4; ++mt)
#pragma unroll
        for (int nt = 0; nt < 4; ++nt)
          acc[mt][nt] = mfma_bf16(af[ks][mt], bf[ks][nt], acc[mt][nt]);
    __builtin_amdgcn_s_setprio(0);
  }

  // ---- epilogue: per-wave 64x64 bf16 tile via LDS, 16B/lane stores ----
  ushort* eL = &sA[0][0] + wave * 4096;
  const int region = n0 >> 9;   // 0=Q, 1=K, 2=V

  if (region < 2) {
#pragma unroll
    for (int nt = 0; nt < 4; ++nt) {
      const float bv = bias[n0 + wn + nt * 16 + col];
      const int cl = nt * 16 + col;
#pragma unroll
      for (int mt = 0; mt < 4; ++mt) {
        const int rb = mt * 16 + quad * 4;
#pragma unroll
        for (int r = 0; r < 4; ++r) {
          const int R = rb + r;
          eL[R * 64 + (((cl >> 3) ^ (R & 7)) * 8) + (cl & 7)] =
              f2bf_bits(acc[mt][nt][r] + bv);
        }
      }
    }
    ushort* __restrict__ Out = (region == 0) ? Qo : Ko;
    const int rgrp = lane >> 3, cch = lane & 7;
    const int phys = cch ^ rgrp;
    const int dbase = (n0 & (D_DIM - 1)) + wn + cch * 8;
#pragma unroll
    for (int j = 0; j < 8; ++j) {
      const int R = j * 8 + rgrp;
      const short8 v = *(const short8*)(&eL[R * 64 + phys * 8]);
      *(short8*)(&Out[(size_t)(m0 + wm + R) * D_DIM + dbase]) = v;
    }
  } else {
#pragma unroll
    for (int nt = 0; nt < 4; ++nt) {
      const float bv = bias[n0 + wn + nt * 16 + col];
      const int dl = nt * 16 + col;
#pragma unroll
      for (int mt = 0; mt < 4; ++mt) {
        const int rb = mt * 16 + quad * 4;
#pragma unroll
        for (int r = 0; r < 4; ++r) {
          const int tl = rb + r;
          eL[dl * 64 + (((tl >> 3) ^ (dl & 7)) * 8) + (tl & 7)] =
              f2bf_bits(acc[mt][nt][r] + bv);
        }
      }
    }
    const int rgrp = lane >> 3, cch = lane & 7;
    const int phys = cch ^ rgrp;
    const int mr0 = m0 + wm;
    const int bb  = mr0 >> 12;
    const int tt0 = (mr0 & (T_SEQ - 1)) + cch * 8;
#pragma unroll
    for (int j = 0; j < 8; ++j) {
      const int dl = j * 8 + rgrp;
      const short8 v = *(const short8*)(&eL[dl * 64 + phys * 8]);
      const int d = (n0 & (D_DIM - 1)) + wn + dl;
      *(short8*)(&Vt[((size_t)bb * D_DIM + d) * T_SEQ + tt0]) = v;
    }
  }
}

// ---------------------------------------------------------------------------
// Kernel 2: banded attention — r6-exact (best measured: 51.6 -> <41us).
//   256 blocks x 512 thr, 64-row tiles, 192-key span; XCD swizzle; PD=4
//   register prefetch in QK^T; V loads issued before softmax barriers
//   (vmcnt never drained); packed-uint P writes; launch_bounds(512,2).
// ---------------------------------------------------------------------------
__global__ __launch_bounds__(512, 2)
void attn_kernel(const ushort* __restrict__ Qb,
                 const ushort* __restrict__ Kb,
                 const ushort* __restrict__ Vtb,
                 float* __restrict__ out) {
  constexpr int SLD = 193;   // fp32 stride (odd) -> conflict-free softmax sweeps
  constexpr int PLD = 200;   // bf16 stride, 400B rows (16B aligned)
  __shared__ float  S[64 * SLD];   // 49408 B
  __shared__ ushort P[64 * PLD];   // 25600 B

  const int tid  = threadIdx.x;
  const int wave = tid >> 6, lane = tid & 63;
  const int col  = lane & 15, quad = lane >> 4;
  // XCD-aware bijective swizzle (grid 256, 8 XCDs -> 32 consecutive tiles/XCD)
  const int l  = (blockIdx.x & 7) * 32 + (blockIdx.x >> 3);
  const int b  = l >> 6;
  const int t0 = (l & 63) * 64;
  const int s0 = t0 - HIST;

  const ushort* Qp = Qb  + (size_t)b * T_SEQ * D_DIM;
  const ushort* Kp = Kb  + (size_t)b * T_SEQ * D_DIM;
  const ushort* Vp = Vtb + (size_t)b * D_DIM * T_SEQ;

  // ---- phase 1: S[64][192] = Q K^T ----
  const int wr = wave >> 2;    // 0..1 : 32-row group
  const int wc = wave & 3;     // 0..3 : 48-col group
  const ushort* qp0 = Qp + (size_t)(t0 + wr * 32 + col) * D_DIM;
  const ushort* qp1 = qp0 + 16 * D_DIM;
  const ushort* kp[3];
#pragma unroll
  for (int st = 0; st < 3; ++st) {
    int sg = s0 + wc * 48 + st * 16 + col;
    sg = sg < 0 ? 0 : sg;                // clamped keys masked in softmax
    kp[st] = Kp + (size_t)sg * D_DIM;
  }

  f32x4 sacc[2][3];
#pragma unroll
  for (int i = 0; i < 2; ++i)
#pragma unroll
    for (int j = 0; j < 3; ++j) sacc[i][j] = (f32x4)0.0f;

  constexpr int PD = 4;                  // prefetch depth (5 loads/iter -> 15 in flight)
  short8 qf[PD][2], kf[PD][3];
#pragma unroll
  for (int d = 0; d < PD; ++d) {
    const int kk = d * 32 + quad * 8;
    qf[d][0] = *(const short8*)(qp0 + kk);
    qf[d][1] = *(const short8*)(qp1 + kk);
#pragma unroll
    for (int st = 0; st < 3; ++st)
      kf[d][st] = *(const short8*)(kp[st] + kk);
  }
#pragma unroll
  for (int ks = 0; ks < 16; ++ks) {      // K = 512 = 16 * 32
    const int slot = ks & 3;             // compile-time (fully unrolled)
    __builtin_amdgcn_s_setprio(1);
#pragma unroll
    for (int st = 0; st < 3; ++st) {
      sacc[0][st] = mfma_bf16(qf[slot][0], kf[slot][st], sacc[0][st]);
      sacc[1][st] = mfma_bf16(qf[slot][1], kf[slot][st], sacc[1][st]);
    }
    __builtin_amdgcn_s_setprio(0);
    if (ks + PD < 16) {
      const int kk = (ks + PD) * 32 + quad * 8;
      qf[slot][0] = *(const short8*)(qp0 + kk);
      qf[slot][1] = *(const short8*)(qp1 + kk);
#pragma unroll
      for (int st = 0; st < 3; ++st)
        kf[slot][st] = *(const short8*)(kp[st] + kk);
    }
  }
  const float scale = 0.04419417382415922f;   // 1/sqrt(512)
#pragma unroll
  for (int mt = 0; mt < 2; ++mt)
#pragma unroll
    for (int st = 0; st < 3; ++st) {
      const int row = wr * 32 + mt * 16 + quad * 4;
      const int c   = wc * 48 + st * 16 + col;
#pragma unroll
      for (int r = 0; r < 4; ++r)
        S[(row + r) * SLD + c] = sacc[mt][st][r] * scale;
    }

  // Issue nt=0 V loads NOW (independent of softmax); they fly across the
  // barriers below because we never drain vmcnt.
  const ushort* vbase = Vp + (size_t)(wave * 64 + col) * T_SEQ;
  short8 vf[2][6];
#pragma unroll
  for (int k = 0; k < 6; ++k) {
    int sg = s0 + k * 32 + quad * 8;
    sg = sg < 0 ? 0 : sg;                // P is 0 there
    vf[0][k] = *(const short8*)(vbase + sg);
  }

  asm volatile("s_waitcnt lgkmcnt(0)" ::: "memory");  // S stores visible
  __builtin_amdgcn_s_barrier();

  // ---- banded softmax: 8 threads per row, 24 cols each ----
  {
    const int row  = tid >> 3, part = tid & 7;
    const int lo = max(row, HIST - t0);   // j_local >= row and key >= 0
    const int hi = row + HIST;            // causal end (<= 191)
    float* Srow = S + row * SLD;
    const int j0 = part * 24;
    float mx = -3.0e38f;
    for (int j = j0; j < j0 + 24; ++j)
      if (j >= lo && j <= hi) mx = fmaxf(mx, Srow[j]);
    mx = fmaxf(mx, __shfl_xor(mx, 1));
    mx = fmaxf(mx, __shfl_xor(mx, 2));
    mx = fmaxf(mx, __shfl_xor(mx, 4));
    float sum = 0.f;
    for (int j = j0; j < j0 + 24; ++j) {
      if (j >= lo && j <= hi) {
        const float e = __expf(Srow[j] - mx);
        Srow[j] = e;
        sum += e;
      }
    }
    sum += __shfl_xor(sum, 1);
    sum += __shfl_xor(sum, 2);
    sum += __shfl_xor(sum, 4);
    const float inv = 1.0f / sum;
    uint* Prow32 = (uint*)(P + row * PLD);   // 400B rows -> 4B aligned
#pragma unroll
    for (int i = 0; i < 12; ++i) {
      const int j = j0 + 2 * i;
      const float v0 = (j     >= lo && j     <= hi) ? Srow[j]     * inv : 0.0f;
      const float v1 = (j + 1 >= lo && j + 1 <= hi) ? Srow[j + 1] * inv : 0.0f;
      Prow32[part * 12 + i] = (uint)f2bf_bits(v0) | ((uint)f2bf_bits(v1) << 16);
    }
  }
  asm volatile("s_waitcnt lgkmcnt(0)" ::: "memory");  // P writes visible
  __builtin_amdgcn_s_barrier();

  // ---- phase 2: O[64][512] = P[64][192] @ V[192][512], 64 d-cols/wave ----
#pragma unroll
  for (int nt = 0; nt < 4; ++nt) {
    const int cb = nt & 1;
    if (nt < 3) {                        // prefetch next nt's V frags
#pragma unroll
      for (int k = 0; k < 6; ++k) {
        int sg = s0 + k * 32 + quad * 8;
        sg = sg < 0 ? 0 : sg;
        vf[cb ^ 1][k] = *(const short8*)(vbase + (size_t)(nt + 1) * 16 * T_SEQ + sg);
      }
    }
    f32x4 oacc[4];
#pragma unroll
    for (int i = 0; i < 4; ++i) oacc[i] = (f32x4)0.0f;
#pragma unroll
    for (int k = 0; k < 6; ++k) {        // 192 = 6 * 32
      __builtin_amdgcn_s_setprio(1);
#pragma unroll
      for (int mt = 0; mt < 4; ++mt) {
        const short8 af = *(const short8*)(&P[(mt * 16 + col) * PLD + k * 32 + quad * 8]);
        oacc[mt] = mfma_bf16(af, vf[cb][k], oacc[mt]);
      }
      __builtin_amdgcn_s_setprio(0);
    }
    const int d = wave * 64 + nt * 16 + col;
#pragma unroll
    for (int mt = 0; mt < 4; ++mt) {
      const int mg = t0 + mt * 16 + quad * 4;
#pragma unroll
      for (int r = 0; r < 4; ++r)
        out[((size_t)b * T_SEQ + mg + r) * D_DIM + d] = oacc[mt][r];
    }
  }
}

// ---------------------------------------------------------------------------
extern "C" void kernel_launch(void* const* d_in, const int* in_sizes, int n_in,
                              void* d_out, int out_size, void* d_ws, size_t ws_size,
                              hipStream_t stream) {
  const float* X    = (const float*)d_in[0];   // (B*T, 512) fp32
  const float* W    = (const float*)d_in[1];   // (1536, 512) fp32
  const float* bias = (const float*)d_in[2];   // (1536,) fp32

  // ws layout (bf16/ushort): Xb | Wb | Q | K | Vt   (~68.7 MB total)
  const size_t NX = (size_t)NBATCH * T_SEQ * D_DIM;   // 8388608
  const size_t NW = (size_t)3 * D_DIM * D_DIM;        // 786432
  ushort* Xb = (ushort*)d_ws;
  ushort* Wb = Xb + NX;
  ushort* Qw = Wb + NW;
  ushort* Kw = Qw + NX;
  ushort* Vw = Kw + NX;

  {
    const int nchunks16 = (int)((NX + NW) / 16);       // 573440
    cvt_kernel<<<nchunks16 / 256, 256, 0, stream>>>(X, W, Xb, Wb);
  }

  dim3 g1(1536), b1(256);   // linear grid; XCD-chunked swizzle in-kernel
  qkv_gemm_kernel<<<g1, b1, 0, stream>>>(Xb, Wb, bias, Qw, Kw, Vw);

  dim3 g2(NBATCH * (T_SEQ / 64)), b2(512);
  attn_kernel<<<g2, b2, 0, stream>>>(Qw, Kw, Vw, (float*)d_out);
}